// Round 1
// baseline (121.025 us; speedup 1.0000x reference)
//
#include <hip/hip_runtime.h>
#include <hip/hip_bf16.h>
#include <math.h>

#define IN_FEAT 4096
#define OUT_FEAT 4096
#define NCOMP 256
#define BATCH 4096
#define TWO_PI_F 6.28318530717958647692f

typedef __attribute__((ext_vector_type(8))) short short8;
typedef __attribute__((ext_vector_type(8))) __bf16 bf16x8;
typedef __attribute__((ext_vector_type(4))) float f32x4;

// round-to-nearest-even f32 -> bf16
__device__ __forceinline__ ushort f2b(float f) {
  union { float f; unsigned u; } v; v.f = f;
  unsigned r = (v.u + 0x7fffu + ((v.u >> 16) & 1u)) >> 16;
  return (ushort)r;
}

__device__ __forceinline__ bf16x8 ld_frag(const ushort* p) {
  short8 s = *(const short8*)p;
  return __builtin_bit_cast(bf16x8, s);
}

__device__ __forceinline__ void gload_lds16(const ushort* g, ushort* l) {
  __builtin_amdgcn_global_load_lds(
      (const __attribute__((address_space(1))) void*)g,
      (__attribute__((address_space(3))) void*)l, 16, 0, 0);
}

// ---------------------------------------------------------------- wsum
__global__ void wsum_kernel(const float* __restrict__ w, float* __restrict__ wsum) {
  float v = w[threadIdx.x];
  #pragma unroll
  for (int off = 32; off > 0; off >>= 1) v += __shfl_down(v, off);
  __shared__ float s[4];
  if ((threadIdx.x & 63) == 0) s[threadIdx.x >> 6] = v;
  __syncthreads();
  if (threadIdx.x == 0) wsum[0] = s[0] + s[1] + s[2] + s[3];
}

// ---------------------------------------------------------------- prep
// Gt[m][i]  = w[m] * exp(-(xi-mu0)^2/(2 v0)) / sqrt(2pi v0)          (bf16)
// GoT[o][m] = exp(-(xo-mu1)^2/(2 v1)) / sqrt(2pi v1) * scale         (bf16)
__global__ __launch_bounds__(256) void prep_kernel(
    const float* __restrict__ mus, const float* __restrict__ lvs,
    const float* __restrict__ w, const float* __restrict__ wsum,
    ushort* __restrict__ Gt, ushort* __restrict__ GoT) {
  int idx = blockIdx.x * 256 + threadIdx.x;
  if (idx < NCOMP * IN_FEAT) {
    int m = idx >> 12, i = idx & (IN_FEAT - 1);
    float v = expf(lvs[2 * m]);
    float d = (float)i * (1.0f / (IN_FEAT - 1)) - mus[2 * m];
    float g = expf(-d * d * (0.5f / v)) * rsqrtf(TWO_PI_F * v) * w[m];
    Gt[idx] = f2b(g);
  } else {
    idx -= NCOMP * IN_FEAT;
    int o = idx >> 8, m = idx & (NCOMP - 1);
    float v = expf(lvs[2 * m + 1]);
    float d = (float)o * (1.0f / (OUT_FEAT - 1)) - mus[2 * m + 1];
    float scale = 1.0f / ((float)IN_FEAT * wsum[0]);
    float g = expf(-d * d * (0.5f / v)) * rsqrtf(TWO_PI_F * v) * scale;
    GoT[idx] = f2b(g);
  }
}

// ---------------------------------------------------------------- GEMM1
// C[4096][256] = x(f32)[4096][4096] @ Gt^T   (Gt is [256][4096], k-contig)
// BM=16, BN=256 (full), BK=32, 4 waves, each wave 16x64
__global__ __launch_bounds__(256) void gemm1_kernel(
    const float* __restrict__ x, const ushort* __restrict__ Gt,
    ushort* __restrict__ C) {
  __shared__ __align__(16) ushort As[16][40];       // +8 pad: 80B rows
  __shared__ __align__(16) ushort Bs[NCOMP * 32];   // [n][k] linear
  const int tid = threadIdx.x;
  const int wid = tid >> 6;
  const int lane = tid & 63;
  const int m0 = blockIdx.x * 16;

  f32x4 acc[4] = {};
  const int arow = tid >> 3, akq = tid & 7;

  for (int k0 = 0; k0 < IN_FEAT; k0 += 32) {
    // A: 16x32 f32 -> bf16 (reg-staged, fused convert)
    if (tid < 128) {
      float4 v = *(const float4*)&x[(size_t)(m0 + arow) * IN_FEAT + k0 + akq * 4];
      ushort4 h;
      h.x = f2b(v.x); h.y = f2b(v.y); h.z = f2b(v.z); h.w = f2b(v.w);
      *(ushort4*)&As[arow][akq * 4] = h;
    }
    // B: 256x32 bf16 via global_load_lds (16 x 1KB chunks, 4/wave)
    #pragma unroll
    for (int q = 0; q < 4; ++q) {
      int row = wid * 64 + q * 16 + (lane >> 2);
      gload_lds16(&Gt[(size_t)row * IN_FEAT + k0 + (lane & 3) * 8],
                  &Bs[(wid * 4 + q) * 512]);
    }
    __syncthreads();

    bf16x8 af = ld_frag(&As[lane & 15][(lane >> 4) * 8]);
    #pragma unroll
    for (int j = 0; j < 4; ++j) {
      bf16x8 bf = ld_frag(&Bs[(wid * 64 + j * 16 + (lane & 15)) * 32 + (lane >> 4) * 8]);
      acc[j] = __builtin_amdgcn_mfma_f32_16x16x32_bf16(af, bf, acc[j], 0, 0, 0);
    }
    __syncthreads();
  }

  #pragma unroll
  for (int j = 0; j < 4; ++j) {
    int col = wid * 64 + j * 16 + (lane & 15);
    #pragma unroll
    for (int r = 0; r < 4; ++r) {
      int row = m0 + (lane >> 4) * 4 + r;
      C[(size_t)row * NCOMP + col] = f2b(acc[j][r]);
    }
  }
}

// ---------------------------------------------------------------- GEMM2
// out[4096][4096](f32) = C[4096][256] @ GoT^T  (GoT is [4096][256], k-contig)
// BM=128, BN=128, BK=32, 4 waves (2x2), each wave 64x64
__global__ __launch_bounds__(256) void gemm2_kernel(
    const ushort* __restrict__ C, const ushort* __restrict__ GoT,
    float* __restrict__ out) {
  __shared__ __align__(16) ushort As[128 * 32];
  __shared__ __align__(16) ushort Bs[128 * 32];
  const int tid = threadIdx.x, wid = tid >> 6, lane = tid & 63;
  const int m0 = blockIdx.y * 128, n0 = blockIdx.x * 128;
  const int wr = (wid >> 1) * 64, wc = (wid & 1) * 64;

  f32x4 acc[4][4] = {};

  for (int k0 = 0; k0 < NCOMP; k0 += 32) {
    #pragma unroll
    for (int q = 0; q < 2; ++q) {
      int chunk = wid * 2 + q;
      int row = chunk * 16 + (lane >> 2), kg = (lane & 3) * 8;
      gload_lds16(&C[(size_t)(m0 + row) * NCOMP + k0 + kg], &As[chunk * 512]);
      gload_lds16(&GoT[(size_t)(n0 + row) * NCOMP + k0 + kg], &Bs[chunk * 512]);
    }
    __syncthreads();

    bf16x8 af[4], bf[4];
    #pragma unroll
    for (int i = 0; i < 4; ++i)
      af[i] = ld_frag(&As[(wr + i * 16 + (lane & 15)) * 32 + (lane >> 4) * 8]);
    #pragma unroll
    for (int j = 0; j < 4; ++j)
      bf[j] = ld_frag(&Bs[(wc + j * 16 + (lane & 15)) * 32 + (lane >> 4) * 8]);
    #pragma unroll
    for (int i = 0; i < 4; ++i)
      #pragma unroll
      for (int j = 0; j < 4; ++j)
        acc[i][j] = __builtin_amdgcn_mfma_f32_16x16x32_bf16(af[i], bf[j], acc[i][j], 0, 0, 0);
    __syncthreads();
  }

  #pragma unroll
  for (int i = 0; i < 4; ++i) {
    #pragma unroll
    for (int r = 0; r < 4; ++r) {
      int row = m0 + wr + i * 16 + (lane >> 4) * 4 + r;
      #pragma unroll
      for (int j = 0; j < 4; ++j)
        out[(size_t)row * OUT_FEAT + n0 + wc + j * 16 + (lane & 15)] = acc[i][j][r];
    }
  }
}

// ---------------------------------------------------------------- launch
extern "C" void kernel_launch(void* const* d_in, const int* in_sizes, int n_in,
                              void* d_out, int out_size, void* d_ws, size_t ws_size,
                              hipStream_t stream) {
  const float* x   = (const float*)d_in[0];
  const float* mus = (const float*)d_in[1];
  const float* lvs = (const float*)d_in[2];
  const float* w   = (const float*)d_in[3];
  float* out = (float*)d_out;

  ushort* Gt   = (ushort*)d_ws;                       // [256][4096] bf16
  ushort* GoT  = Gt  + (size_t)NCOMP * IN_FEAT;       // [4096][256] bf16
  ushort* Cb   = GoT + (size_t)OUT_FEAT * NCOMP;      // [4096][256] bf16
  float*  wsum = (float*)(Cb + (size_t)BATCH * NCOMP);

  wsum_kernel<<<1, 256, 0, stream>>>(w, wsum);
  prep_kernel<<<(NCOMP * IN_FEAT + OUT_FEAT * NCOMP) / 256, 256, 0, stream>>>(
      mus, lvs, w, wsum, Gt, GoT);
  gemm1_kernel<<<BATCH / 16, 256, 0, stream>>>(x, Gt, Cb);
  gemm2_kernel<<<dim3(OUT_FEAT / 128, BATCH / 128), 256, 0, stream>>>(Cb, GoT, out);
}

// Round 2
// 67.245 us; speedup vs baseline: 1.7998x; 1.7998x over previous
//
#include <hip/hip_runtime.h>
#include <hip/hip_bf16.h>
#include <math.h>

#define IN_FEAT 4096
#define OUT_FEAT 4096
#define NCOMP 256
#define BATCH 4096
#define TWO_PI_F 6.28318530717958647692f

typedef __attribute__((ext_vector_type(8))) short short8;
typedef __attribute__((ext_vector_type(8))) __bf16 bf16x8;
typedef __attribute__((ext_vector_type(4))) float f32x4;

// round-to-nearest-even f32 -> bf16
__device__ __forceinline__ ushort f2b(float f) {
  union { float f; unsigned u; } v; v.f = f;
  unsigned r = (v.u + 0x7fffu + ((v.u >> 16) & 1u)) >> 16;
  return (ushort)r;
}

__device__ __forceinline__ bf16x8 ld_frag(const void* p) {
  short8 s = *(const short8*)p;
  return __builtin_bit_cast(bf16x8, s);
}

__device__ __forceinline__ void gload_lds16(const ushort* g, ushort* l) {
  __builtin_amdgcn_global_load_lds(
      (const __attribute__((address_space(1))) void*)g,
      (__attribute__((address_space(3))) void*)l, 16, 0, 0);
}

__device__ __forceinline__ void cvt_store8(void* dst, float4 a, float4 b) {
  short8 h;
  h[0] = (short)f2b(a.x); h[1] = (short)f2b(a.y);
  h[2] = (short)f2b(a.z); h[3] = (short)f2b(a.w);
  h[4] = (short)f2b(b.x); h[5] = (short)f2b(b.y);
  h[6] = (short)f2b(b.z); h[7] = (short)f2b(b.w);
  *(short8*)dst = h;
}

// ---------------------------------------------------------------- wsum
__global__ void wsum_kernel(const float* __restrict__ w, float* __restrict__ wsum) {
  float v = w[threadIdx.x];
  #pragma unroll
  for (int off = 32; off > 0; off >>= 1) v += __shfl_down(v, off);
  __shared__ float s[4];
  if ((threadIdx.x & 63) == 0) s[threadIdx.x >> 6] = v;
  __syncthreads();
  if (threadIdx.x == 0) wsum[0] = s[0] + s[1] + s[2] + s[3];
}

// ---------------------------------------------------------------- prep
__global__ __launch_bounds__(256) void prep_kernel(
    const float* __restrict__ mus, const float* __restrict__ lvs,
    const float* __restrict__ w, const float* __restrict__ wsum,
    ushort* __restrict__ Gt, ushort* __restrict__ GoT) {
  int idx = blockIdx.x * 256 + threadIdx.x;
  if (idx < NCOMP * IN_FEAT) {
    int m = idx >> 12, i = idx & (IN_FEAT - 1);
    float v = expf(lvs[2 * m]);
    float d = (float)i * (1.0f / (IN_FEAT - 1)) - mus[2 * m];
    float g = expf(-d * d * (0.5f / v)) * rsqrtf(TWO_PI_F * v) * w[m];
    Gt[idx] = f2b(g);
  } else {
    idx -= NCOMP * IN_FEAT;
    int o = idx >> 8, m = idx & (NCOMP - 1);
    float v = expf(lvs[2 * m + 1]);
    float d = (float)o * (1.0f / (OUT_FEAT - 1)) - mus[2 * m + 1];
    float scale = 1.0f / ((float)IN_FEAT * wsum[0]);
    float g = expf(-d * d * (0.5f / v)) * rsqrtf(TWO_PI_F * v) * scale;
    GoT[idx] = f2b(g);
  }
}

// ---------------------------------------------------------------- GEMM1
// Cpart[ks][4096][256] += x[rows, kchunk] @ Gt^T[kchunk, 256]
// BM=32, BN=256 (full), BK=32, split-K over gridDim.y, dbuf LDS, XOR swizzle.
#define G1_AUS 1024   // 32 rows * 32 k (ushort)
#define G1_BUS 8192   // 256 rows * 32 k
#define G1_BUF (G1_AUS + G1_BUS)

__global__ __launch_bounds__(256) void gemm1_kernel(
    const float* __restrict__ x, const ushort* __restrict__ Gt,
    float* __restrict__ Cpart) {
  __shared__ __align__(16) ushort lds[2 * G1_BUF];  // 36 KB
  const int tid = threadIdx.x, wid = tid >> 6, lane = tid & 63;
  const int m0 = blockIdx.x * 32;
  const int kr = IN_FEAT / gridDim.y;
  const int kb0 = blockIdx.y * kr;
  const int NT = kr >> 5;

  f32x4 acc[2][4] = {};

  // A staging (tid<128): 32 rows x 32 k, 8 f32 -> 8 bf16 per thread
  const int arow = tid >> 2, akq = tid & 3;
  const size_t axbase = (size_t)(m0 + arow) * IN_FEAT + akq * 8;
  const int abyte = arow * 64 + ((akq * 16) ^ (((arow >> 1) & 3) << 4));
  // B staging: 16 chunks of 1KB (16 rows x 64B); 4 per wave.
  // Pre-swizzled global source so linear LDS dest == swizzled layout.
  const int brow = lane >> 2;
  const int bsrc = (((lane & 3) ^ ((lane >> 3) & 3)) << 3);  // ushort offset
  // fragment-read swizzle (same for A and B; 64B rows)
  const int fswz = ((lane >> 4) * 16) ^ ((((lane & 15) >> 1) & 3) << 4);

  // prologue: stage tile 0 into buf 0
  {
    float4 a0, a1;
    if (tid < 128) {
      a0 = *(const float4*)&x[axbase + kb0];
      a1 = *(const float4*)&x[axbase + kb0 + 4];
    }
    #pragma unroll
    for (int q = 0; q < 4; ++q) {
      int cw = wid * 4 + q;
      int n = cw * 16 + brow;
      gload_lds16(&Gt[(size_t)n * IN_FEAT + kb0 + bsrc], &lds[G1_AUS + cw * 512]);
    }
    if (tid < 128) cvt_store8((char*)lds + abyte, a0, a1);
  }
  __syncthreads();

  for (int t = 0; t < NT; ++t) {
    const char* A = (const char*)&lds[(t & 1) * G1_BUF];
    const char* B = A + G1_AUS * 2;
    char* An = (char*)&lds[((t + 1) & 1) * G1_BUF];
    const bool last = (t == NT - 1);

    float4 a0, a1;
    if (!last) {  // issue next-tile loads early (hide under compute)
      int kb = kb0 + (t + 1) * 32;
      if (tid < 128) {
        a0 = *(const float4*)&x[axbase + kb];
        a1 = *(const float4*)&x[axbase + kb + 4];
      }
      #pragma unroll
      for (int q = 0; q < 4; ++q) {
        int cw = wid * 4 + q;
        int n = cw * 16 + brow;
        gload_lds16(&Gt[(size_t)n * IN_FEAT + kb + bsrc],
                    (ushort*)(An + G1_AUS * 2) + cw * 512);
      }
    }

    bf16x8 af[2], bf[4];
    #pragma unroll
    for (int mi = 0; mi < 2; ++mi)
      af[mi] = ld_frag(A + (mi * 16 + (lane & 15)) * 64 + fswz);
    #pragma unroll
    for (int nj = 0; nj < 4; ++nj)
      bf[nj] = ld_frag(B + (wid * 64 + nj * 16 + (lane & 15)) * 64 + fswz);
    #pragma unroll
    for (int mi = 0; mi < 2; ++mi)
      #pragma unroll
      for (int nj = 0; nj < 4; ++nj)
        acc[mi][nj] = __builtin_amdgcn_mfma_f32_16x16x32_bf16(af[mi], bf[nj], acc[mi][nj], 0, 0, 0);

    if (!last && tid < 128) cvt_store8(An + abyte, a0, a1);
    __syncthreads();
  }

  float* Cp = Cpart + (size_t)blockIdx.y * ((size_t)BATCH * NCOMP);
  #pragma unroll
  for (int mi = 0; mi < 2; ++mi)
    #pragma unroll
    for (int nj = 0; nj < 4; ++nj)
      #pragma unroll
      for (int r = 0; r < 4; ++r) {
        int row = m0 + mi * 16 + (lane >> 4) * 4 + r;
        int col = wid * 64 + nj * 16 + (lane & 15);
        Cp[(size_t)row * NCOMP + col] = acc[mi][nj][r];
      }
}

// ---------------------------------------------------------------- reduce
__global__ __launch_bounds__(256) void reduce_kernel(
    const float* __restrict__ Cp, ushort* __restrict__ Cb, int nsplit) {
  size_t i = ((size_t)blockIdx.x * 256 + threadIdx.x) * 4;
  f32x4 s = *(const f32x4*)&Cp[i];
  for (int p = 1; p < nsplit; ++p)
    s += *(const f32x4*)&Cp[(size_t)p * BATCH * NCOMP + i];
  ushort4 h;
  h.x = f2b(s[0]); h.y = f2b(s[1]); h.z = f2b(s[2]); h.w = f2b(s[3]);
  *(ushort4*)&Cb[i] = h;
}

// ---------------------------------------------------------------- GEMM2
// out[4096][4096](f32) = Cb[4096][256] @ GoT^T ; BM=BN=128, BK=32, swizzled LDS
__global__ __launch_bounds__(256) void gemm2_kernel(
    const ushort* __restrict__ Cb, const ushort* __restrict__ GoT,
    float* __restrict__ out) {
  __shared__ __align__(16) ushort As[128 * 32];
  __shared__ __align__(16) ushort Bs[128 * 32];
  const int tid = threadIdx.x, wid = tid >> 6, lane = tid & 63;
  const int m0 = blockIdx.y * 128, n0 = blockIdx.x * 128;
  const int wr = (wid >> 1) * 64, wc = (wid & 1) * 64;
  const int srow = lane >> 2;
  const int srck = (((lane & 3) ^ ((lane >> 3) & 3)) << 3);  // ushort offset
  const int fswz = ((lane >> 4) * 16) ^ ((((lane & 15) >> 1) & 3) << 4);

  f32x4 acc[4][4] = {};

  for (int k0 = 0; k0 < NCOMP; k0 += 32) {
    #pragma unroll
    for (int q = 0; q < 2; ++q) {
      int cw = wid * 2 + q;
      int row = cw * 16 + srow;
      gload_lds16(&Cb[(size_t)(m0 + row) * NCOMP + k0 + srck], &As[cw * 512]);
      gload_lds16(&GoT[(size_t)(n0 + row) * NCOMP + k0 + srck], &Bs[cw * 512]);
    }
    __syncthreads();

    bf16x8 af[4], bf[4];
    #pragma unroll
    for (int i = 0; i < 4; ++i)
      af[i] = ld_frag((const char*)As + (wr + i * 16 + (lane & 15)) * 64 + fswz);
    #pragma unroll
    for (int j = 0; j < 4; ++j)
      bf[j] = ld_frag((const char*)Bs + (wc + j * 16 + (lane & 15)) * 64 + fswz);
    #pragma unroll
    for (int i = 0; i < 4; ++i)
      #pragma unroll
      for (int j = 0; j < 4; ++j)
        acc[i][j] = __builtin_amdgcn_mfma_f32_16x16x32_bf16(af[i], bf[j], acc[i][j], 0, 0, 0);
    __syncthreads();
  }

  #pragma unroll
  for (int i = 0; i < 4; ++i)
    #pragma unroll
    for (int r = 0; r < 4; ++r) {
      int row = m0 + wr + i * 16 + (lane >> 4) * 4 + r;
      #pragma unroll
      for (int j = 0; j < 4; ++j)
        out[(size_t)row * OUT_FEAT + n0 + wc + j * 16 + (lane & 15)] = acc[i][j][r];
    }
}

// ---------------------------------------------------------------- launch
extern "C" void kernel_launch(void* const* d_in, const int* in_sizes, int n_in,
                              void* d_out, int out_size, void* d_ws, size_t ws_size,
                              hipStream_t stream) {
  const float* x   = (const float*)d_in[0];
  const float* mus = (const float*)d_in[1];
  const float* lvs = (const float*)d_in[2];
  const float* w   = (const float*)d_in[3];
  float* out = (float*)d_out;

  ushort* Gt   = (ushort*)d_ws;                      // [256][4096] bf16, 2 MiB
  ushort* GoT  = Gt  + (size_t)NCOMP * IN_FEAT;      // [4096][256] bf16, 2 MiB
  ushort* Cb   = GoT + (size_t)OUT_FEAT * NCOMP;     // [4096][256] bf16, 2 MiB
  float*  Cpart = (float*)(Cb + (size_t)BATCH * NCOMP);
  // pick split-K factor that fits the workspace
  size_t base = (size_t)6 * 1024 * 1024;
  int nsplit = 1;
  if (ws_size >= base + 4u * 4 * 1024 * 1024 + 64) nsplit = 4;
  else if (ws_size >= base + 2u * 4 * 1024 * 1024 + 64) nsplit = 2;
  float* wsum = (float*)(Cpart + (size_t)nsplit * BATCH * NCOMP);

  wsum_kernel<<<1, 256, 0, stream>>>(w, wsum);
  prep_kernel<<<(NCOMP * IN_FEAT + OUT_FEAT * NCOMP) / 256, 256, 0, stream>>>(
      mus, lvs, w, wsum, Gt, GoT);
  gemm1_kernel<<<dim3(BATCH / 32, nsplit), 256, 0, stream>>>(x, Gt, Cpart);
  reduce_kernel<<<(BATCH * NCOMP / 4) / 256, 256, 0, stream>>>(Cpart, Cb, nsplit);
  gemm2_kernel<<<dim3(OUT_FEAT / 128, BATCH / 128), 256, 0, stream>>>(Cb, GoT, out);
}

// Round 3
// 61.544 us; speedup vs baseline: 1.9665x; 1.0926x over previous
//
#include <hip/hip_runtime.h>
#include <hip/hip_bf16.h>
#include <math.h>

#define IN_FEAT 4096
#define OUT_FEAT 4096
#define NCOMP 256
#define BATCH 4096
#define TWO_PI_F 6.28318530717958647692f

typedef __attribute__((ext_vector_type(8))) short short8;
typedef __attribute__((ext_vector_type(8))) __bf16 bf16x8;
typedef __attribute__((ext_vector_type(4))) float f32x4;

// round-to-nearest-even f32 -> bf16
__device__ __forceinline__ ushort f2b(float f) {
  union { float f; unsigned u; } v; v.f = f;
  unsigned r = (v.u + 0x7fffu + ((v.u >> 16) & 1u)) >> 16;
  return (ushort)r;
}

__device__ __forceinline__ float b2f(short s) {
  union { unsigned u; float f; } v; v.u = ((unsigned)(ushort)s) << 16;
  return v.f;
}

__device__ __forceinline__ bf16x8 ld_frag(const void* p) {
  short8 s = *(const short8*)p;
  return __builtin_bit_cast(bf16x8, s);
}

__device__ __forceinline__ bf16x8 cvt8(float4 a, float4 b) {
  short8 h;
  h[0] = (short)f2b(a.x); h[1] = (short)f2b(a.y);
  h[2] = (short)f2b(a.z); h[3] = (short)f2b(a.w);
  h[4] = (short)f2b(b.x); h[5] = (short)f2b(b.y);
  h[6] = (short)f2b(b.z); h[7] = (short)f2b(b.w);
  return __builtin_bit_cast(bf16x8, h);
}

__device__ __forceinline__ void gload_lds16(const ushort* g, ushort* l) {
  __builtin_amdgcn_global_load_lds(
      (const __attribute__((address_space(1))) void*)g,
      (__attribute__((address_space(3))) void*)l, 16, 0, 0);
}

// ---------------------------------------------------------------- wsum
__global__ void wsum_kernel(const float* __restrict__ w, float* __restrict__ wsum) {
  float v = w[threadIdx.x];
  #pragma unroll
  for (int off = 32; off > 0; off >>= 1) v += __shfl_down(v, off);
  __shared__ float s[4];
  if ((threadIdx.x & 63) == 0) s[threadIdx.x >> 6] = v;
  __syncthreads();
  if (threadIdx.x == 0) wsum[0] = s[0] + s[1] + s[2] + s[3];
}

// ---------------------------------------------------------------- prep
__global__ __launch_bounds__(256) void prep_kernel(
    const float* __restrict__ mus, const float* __restrict__ lvs,
    const float* __restrict__ w, const float* __restrict__ wsum,
    ushort* __restrict__ Gt, ushort* __restrict__ GoT) {
  int idx = blockIdx.x * 256 + threadIdx.x;
  if (idx < NCOMP * IN_FEAT) {
    int m = idx >> 12, i = idx & (IN_FEAT - 1);
    float v = expf(lvs[2 * m]);
    float d = (float)i * (1.0f / (IN_FEAT - 1)) - mus[2 * m];
    float g = expf(-d * d * (0.5f / v)) * rsqrtf(TWO_PI_F * v) * w[m];
    Gt[idx] = f2b(g);
  } else {
    idx -= NCOMP * IN_FEAT;
    int o = idx >> 8, m = idx & (NCOMP - 1);
    float v = expf(lvs[2 * m + 1]);
    float d = (float)o * (1.0f / (OUT_FEAT - 1)) - mus[2 * m + 1];
    float scale = 1.0f / ((float)IN_FEAT * wsum[0]);
    float g = expf(-d * d * (0.5f / v)) * rsqrtf(TWO_PI_F * v) * scale;
    GoT[idx] = f2b(g);
  }
}

// ---------------------------------------------------------------- GEMM1
// Cpart[split][4096][256](bf16) = x[rows, kchunk] @ Gt^T[kchunk, 256]
// BM=64 (4 waves x m16), BN=256 (full). A: global->reg, fused f32->bf16,
// NO LDS, NO barrier dependence. B: LDS, stage-level dbuf (64-k stages),
// barriers only once per 64-k stage. Split-K over gridDim.y.
__global__ __launch_bounds__(256, 2) void gemm1_kernel(
    const float* __restrict__ x, const ushort* __restrict__ Gt,
    ushort* __restrict__ Cpart) {
  __shared__ __align__(16) ushort Bs[32768];  // 2 buf x [2 kstep][256 n][32 k] = 64 KB
  const int tid = threadIdx.x, wid = tid >> 6, lane = tid & 63;
  const int m0 = blockIdx.x * 64;
  const int kr = IN_FEAT / gridDim.y;
  const int kb0 = blockIdx.y * kr;
  const int NT = kr >> 6;  // stages of 64 k

  f32x4 acc[16] = {};

  // B staging: 32 chunks of 1KB per stage, 8/wave. chunk c: s=c>>4, nb=c&15
  const int brow = lane >> 2;
  const int bswz = (((lane & 3) ^ ((lane >> 3) & 3)) << 3);  // ushort units
  // fragment-read swizzle (64B rows)
  const int fswz = ((lane >> 4) << 4) ^ ((((lane & 15) >> 1) & 3) << 4);  // bytes

  // A: per-lane row/k-quarter for the 16x16x32 A fragment
  const float* xp = &x[(size_t)(m0 + wid * 16 + (lane & 15)) * IN_FEAT +
                       kb0 + ((lane >> 4) << 3)];

  #define G1_STAGE(buf, kb)                                                  \
    _Pragma("unroll")                                                        \
    for (int q = 0; q < 8; ++q) {                                            \
      int c = wid * 8 + q, s_ = c >> 4, nb = c & 15;                         \
      gload_lds16(&Gt[(size_t)(nb * 16 + brow) * IN_FEAT + (kb) + s_ * 32 + bswz], \
                  &Bs[(buf) * 16384 + s_ * 8192 + nb * 512]);                \
    }

  G1_STAGE(0, kb0)
  __syncthreads();

  for (int t = 0; t < NT; ++t) {
    // x loads for both k-steps of this stage: issue first, hide under compute
    float4 u0 = *(const float4*)(xp + t * 64);
    float4 u1 = *(const float4*)(xp + t * 64 + 4);
    float4 u2 = *(const float4*)(xp + t * 64 + 32);
    float4 u3 = *(const float4*)(xp + t * 64 + 36);
    if (t + 1 < NT) { G1_STAGE((t + 1) & 1, kb0 + (t + 1) * 64) }

    const char* Bb = (const char*)&Bs[(t & 1) * 16384];
    bf16x8 af0 = cvt8(u0, u1);
    #pragma unroll
    for (int j = 0; j < 16; ++j) {
      bf16x8 bf = ld_frag(Bb + (j * 16 + (lane & 15)) * 64 + fswz);
      acc[j] = __builtin_amdgcn_mfma_f32_16x16x32_bf16(af0, bf, acc[j], 0, 0, 0);
    }
    bf16x8 af1 = cvt8(u2, u3);
    #pragma unroll
    for (int j = 0; j < 16; ++j) {
      bf16x8 bf = ld_frag(Bb + 16384 + (j * 16 + (lane & 15)) * 64 + fswz);
      acc[j] = __builtin_amdgcn_mfma_f32_16x16x32_bf16(af1, bf, acc[j], 0, 0, 0);
    }
    __syncthreads();
  }
  #undef G1_STAGE

  ushort* Cp = Cpart + (size_t)blockIdx.y * ((size_t)BATCH * NCOMP);
  #pragma unroll
  for (int j = 0; j < 16; ++j)
    #pragma unroll
    for (int r = 0; r < 4; ++r) {
      int row = m0 + wid * 16 + (lane >> 4) * 4 + r;
      int col = j * 16 + (lane & 15);
      Cp[(size_t)row * NCOMP + col] = f2b(acc[j][r]);
    }
}

// ---------------------------------------------------------------- reduce
// Cb = round_bf16( sum_p Cpart[p] )  (bf16 partials, f32 accumulate)
__global__ __launch_bounds__(256) void reduce_kernel(
    const ushort* __restrict__ Cp, ushort* __restrict__ Cb, int nsplit) {
  size_t i = ((size_t)blockIdx.x * 256 + threadIdx.x) * 8;
  float s[8] = {0.f, 0.f, 0.f, 0.f, 0.f, 0.f, 0.f, 0.f};
  for (int p = 0; p < nsplit; ++p) {
    short8 v = *(const short8*)&Cp[(size_t)p * BATCH * NCOMP + i];
    #pragma unroll
    for (int e = 0; e < 8; ++e) s[e] += b2f(v[e]);
  }
  short8 h;
  #pragma unroll
  for (int e = 0; e < 8; ++e) h[e] = (short)f2b(s[e]);
  *(short8*)&Cb[i] = h;
}

// ---------------------------------------------------------------- GEMM2
// out[4096][4096](f32) = Cb[4096][256] @ GoT^T ; BM=BN=128, BK=32, swizzled LDS
__global__ __launch_bounds__(256) void gemm2_kernel(
    const ushort* __restrict__ Cb, const ushort* __restrict__ GoT,
    float* __restrict__ out) {
  __shared__ __align__(16) ushort As[128 * 32];
  __shared__ __align__(16) ushort Bs[128 * 32];
  const int tid = threadIdx.x, wid = tid >> 6, lane = tid & 63;
  const int m0 = blockIdx.y * 128, n0 = blockIdx.x * 128;
  const int wr = (wid >> 1) * 64, wc = (wid & 1) * 64;
  const int srow = lane >> 2;
  const int srck = (((lane & 3) ^ ((lane >> 3) & 3)) << 3);
  const int fswz = ((lane >> 4) << 4) ^ ((((lane & 15) >> 1) & 3) << 4);

  f32x4 acc[4][4] = {};

  for (int k0 = 0; k0 < NCOMP; k0 += 32) {
    #pragma unroll
    for (int q = 0; q < 2; ++q) {
      int cw = wid * 2 + q;
      int row = cw * 16 + srow;
      gload_lds16(&Cb[(size_t)(m0 + row) * NCOMP + k0 + srck], &As[cw * 512]);
      gload_lds16(&GoT[(size_t)(n0 + row) * NCOMP + k0 + srck], &Bs[cw * 512]);
    }
    __syncthreads();

    bf16x8 af[4], bf[4];
    #pragma unroll
    for (int i = 0; i < 4; ++i)
      af[i] = ld_frag((const char*)As + (wr + i * 16 + (lane & 15)) * 64 + fswz);
    #pragma unroll
    for (int j = 0; j < 4; ++j)
      bf[j] = ld_frag((const char*)Bs + (wc + j * 16 + (lane & 15)) * 64 + fswz);
    #pragma unroll
    for (int i = 0; i < 4; ++i)
      #pragma unroll
      for (int j = 0; j < 4; ++j)
        acc[i][j] = __builtin_amdgcn_mfma_f32_16x16x32_bf16(af[i], bf[j], acc[i][j], 0, 0, 0);
    __syncthreads();
  }

  #pragma unroll
  for (int i = 0; i < 4; ++i)
    #pragma unroll
    for (int r = 0; r < 4; ++r) {
      int row = m0 + wr + i * 16 + (lane >> 4) * 4 + r;
      #pragma unroll
      for (int j = 0; j < 4; ++j)
        out[(size_t)row * OUT_FEAT + n0 + wc + j * 16 + (lane & 15)] = acc[i][j][r];
    }
}

// ---------------------------------------------------------------- launch
extern "C" void kernel_launch(void* const* d_in, const int* in_sizes, int n_in,
                              void* d_out, int out_size, void* d_ws, size_t ws_size,
                              hipStream_t stream) {
  const float* x   = (const float*)d_in[0];
  const float* mus = (const float*)d_in[1];
  const float* lvs = (const float*)d_in[2];
  const float* w   = (const float*)d_in[3];
  float* out = (float*)d_out;

  ushort* Gt  = (ushort*)d_ws;                      // [256][4096] bf16, 2 MiB
  ushort* GoT = Gt  + (size_t)NCOMP * IN_FEAT;      // [4096][256] bf16, 2 MiB
  ushort* Cb  = GoT + (size_t)OUT_FEAT * NCOMP;     // [4096][256] bf16, 2 MiB
  ushort* Cpart = Cb + (size_t)BATCH * NCOMP;       // nsplit x 2 MiB (bf16)

  size_t base = (size_t)6 * 1024 * 1024;
  int nsplit = 8;
  while (nsplit > 1 &&
         ws_size < base + (size_t)nsplit * 2 * 1024 * 1024 + 64)
    nsplit >>= 1;
  float* wsum = (float*)(Cpart + (size_t)nsplit * BATCH * NCOMP);

  wsum_kernel<<<1, 256, 0, stream>>>(w, wsum);
  prep_kernel<<<(NCOMP * IN_FEAT + OUT_FEAT * NCOMP) / 256, 256, 0, stream>>>(
      mus, lvs, w, wsum, Gt, GoT);
  gemm1_kernel<<<dim3(BATCH / 64, nsplit), 256, 0, stream>>>(x, Gt, Cpart);
  reduce_kernel<<<(BATCH * NCOMP / 8) / 256, 256, 0, stream>>>(Cpart, Cb, nsplit);
  gemm2_kernel<<<dim3(OUT_FEAT / 128, BATCH / 128), 256, 0, stream>>>(Cb, GoT, out);
}

// Round 4
// 60.773 us; speedup vs baseline: 1.9914x; 1.0127x over previous
//
#include <hip/hip_runtime.h>
#include <hip/hip_bf16.h>
#include <math.h>

#define IN_FEAT 4096
#define OUT_FEAT 4096
#define NCOMP 256
#define BATCH 4096
#define TWO_PI_F 6.28318530717958647692f

typedef __attribute__((ext_vector_type(8))) short short8;
typedef __attribute__((ext_vector_type(8))) __bf16 bf16x8;
typedef __attribute__((ext_vector_type(4))) float f32x4;

// round-to-nearest-even f32 -> bf16
__device__ __forceinline__ ushort f2b(float f) {
  union { float f; unsigned u; } v; v.f = f;
  unsigned r = (v.u + 0x7fffu + ((v.u >> 16) & 1u)) >> 16;
  return (ushort)r;
}

__device__ __forceinline__ float b2f(short s) {
  union { unsigned u; float f; } v; v.u = ((unsigned)(ushort)s) << 16;
  return v.f;
}

__device__ __forceinline__ bf16x8 ld_frag(const void* p) {
  short8 s = *(const short8*)p;
  return __builtin_bit_cast(bf16x8, s);
}

__device__ __forceinline__ short8 cvt8(float4 a, float4 b) {
  short8 h;
  h[0] = (short)f2b(a.x); h[1] = (short)f2b(a.y);
  h[2] = (short)f2b(a.z); h[3] = (short)f2b(a.w);
  h[4] = (short)f2b(b.x); h[5] = (short)f2b(b.y);
  h[6] = (short)f2b(b.z); h[7] = (short)f2b(b.w);
  return h;
}

__device__ __forceinline__ void gload_lds16(const ushort* g, ushort* l) {
  __builtin_amdgcn_global_load_lds(
      (const __attribute__((address_space(1))) void*)g,
      (__attribute__((address_space(3))) void*)l, 16, 0, 0);
}

// ---------------------------------------------------------------- prep
// Gt[m][i]  = w[m] * pdf(xi; mu0, v0)   (bf16)
// GoT[o][m] = pdf(xo; mu1, v1)          (bf16, UNSCALED - scale in gemm2)
__global__ __launch_bounds__(256) void prep_kernel(
    const float* __restrict__ mus, const float* __restrict__ lvs,
    const float* __restrict__ w,
    ushort* __restrict__ Gt, ushort* __restrict__ GoT) {
  int idx = blockIdx.x * 256 + threadIdx.x;
  if (idx < NCOMP * IN_FEAT) {
    int m = idx >> 12, i = idx & (IN_FEAT - 1);
    float v = expf(lvs[2 * m]);
    float d = (float)i * (1.0f / (IN_FEAT - 1)) - mus[2 * m];
    float g = expf(-d * d * (0.5f / v)) * rsqrtf(TWO_PI_F * v) * w[m];
    Gt[idx] = f2b(g);
  } else {
    idx -= NCOMP * IN_FEAT;
    int o = idx >> 8, m = idx & (NCOMP - 1);
    float v = expf(lvs[2 * m + 1]);
    float d = (float)o * (1.0f / (OUT_FEAT - 1)) - mus[2 * m + 1];
    float g = expf(-d * d * (0.5f / v)) * rsqrtf(TWO_PI_F * v);
    GoT[idx] = f2b(g);
  }
}

// ---------------------------------------------------------------- GEMM1
// Cpart[split][4096][256](bf16) = x[64-band, kchunk] @ Gt^T
// BM=64, BN=256, stage=32k, dbuf LDS (20 KB/stage -> 40 KB -> 4 blocks/CU).
// A: reg-load f32 -> cvt bf16 -> swizzled ds_write (issue-early/write-late).
// B: global_load_lds with pre-swizzled source. One barrier per stage.
template<int NS>
__global__ __launch_bounds__(256, 4) void gemm1_kernel(
    const float* __restrict__ x, const ushort* __restrict__ Gt,
    ushort* __restrict__ Cpart) {
  constexpr int KR = IN_FEAT / NS;
  constexpr int NT = KR / 32;
  // per buf: B = 256n x 32k bf16 = 16 KB, then A = 64m x 32k bf16 = 4 KB
  __shared__ __align__(16) ushort lds[2 * 10240];  // 40 KB
  const int tid = threadIdx.x, wid = tid >> 6, lane = tid & 63;
  const int m0 = blockIdx.x * 64;
  const int kb0 = blockIdx.y * KR;

  f32x4 acc[16] = {};

  // B staging: 16 chunks of 1 KB (16 n-rows x 64 B); 4 per wave
  const int brow = lane >> 2;
  const int bswz = (((lane & 3) ^ ((lane >> 3) & 3)) << 3);  // ushort units
  // fragment read swizzle (64 B rows)
  const int fswz = ((lane >> 4) << 4) ^ ((((lane & 15) >> 1) & 3) << 4);

  // A staging: 64 rows x 32 k f32 -> 8 f32/thread (row=tid>>2, slot=tid&3)
  const int arow = tid >> 2, aslot = tid & 3;
  const float* asrc = &x[(size_t)(m0 + arow) * IN_FEAT + kb0 + aslot * 8];
  const int abyte = arow * 64 + ((aslot << 4) ^ (((arow >> 1) & 3) << 4));

  #define STAGE_B(buf, kb)                                                   \
    _Pragma("unroll")                                                        \
    for (int q = 0; q < 4; ++q) {                                            \
      int nb = wid * 4 + q;                                                  \
      gload_lds16(&Gt[(size_t)(nb * 16 + brow) * IN_FEAT + (kb) + bswz],     \
                  &lds[(buf) * 10240 + nb * 512]);                           \
    }

  // prologue: stage tile 0
  STAGE_B(0, kb0)
  {
    float4 a0 = *(const float4*)asrc;
    float4 a1 = *(const float4*)(asrc + 4);
    *(short8*)((char*)lds + 16384 + abyte) = cvt8(a0, a1);
  }
  __syncthreads();

  for (int t = 0; t < NT; ++t) {
    float4 px0, px1;
    if (t + 1 < NT) {  // issue next-stage loads first (a full stage to land)
      STAGE_B((t + 1) & 1, kb0 + (t + 1) * 32)
      px0 = *(const float4*)(asrc + (t + 1) * 32);
      px1 = *(const float4*)(asrc + (t + 1) * 32 + 4);
    }
    const char* base = (const char*)lds + (t & 1) * 20480;
    bf16x8 af = ld_frag(base + 16384 + (wid * 16 + (lane & 15)) * 64 + fswz);
    #pragma unroll
    for (int nj = 0; nj < 16; ++nj) {
      bf16x8 bf = ld_frag(base + (nj * 16 + (lane & 15)) * 64 + fswz);
      acc[nj] = __builtin_amdgcn_mfma_f32_16x16x32_bf16(af, bf, acc[nj], 0, 0, 0);
    }
    if (t + 1 < NT)  // write-late: cvt + swizzled ds_write into next buf
      *(short8*)((char*)lds + ((t + 1) & 1) * 20480 + 16384 + abyte) =
          cvt8(px0, px1);
    __syncthreads();
  }
  #undef STAGE_B

  ushort* Cp = Cpart + (size_t)blockIdx.y * ((size_t)BATCH * NCOMP);
  #pragma unroll
  for (int nj = 0; nj < 16; ++nj)
    #pragma unroll
    for (int r = 0; r < 4; ++r) {
      int row = m0 + wid * 16 + (lane >> 4) * 4 + r;
      int col = nj * 16 + (lane & 15);
      Cp[(size_t)row * NCOMP + col] = f2b(acc[nj][r]);
    }
}

// ---------------------------------------------------------------- reduce
// In-place: Cp[0] <- round_bf16( sum_p Cp[p] )  (f32 accumulate)
template<int NS>
__global__ __launch_bounds__(256) void reduce_kernel(ushort* __restrict__ Cp) {
  size_t i = ((size_t)blockIdx.x * 256 + threadIdx.x) * 8;
  float s[8] = {};
  #pragma unroll
  for (int p = 0; p < NS; ++p) {
    short8 v = *(const short8*)&Cp[(size_t)p * BATCH * NCOMP + i];
    #pragma unroll
    for (int e = 0; e < 8; ++e) s[e] += b2f(v[e]);
  }
  short8 h;
  #pragma unroll
  for (int e = 0; e < 8; ++e) h[e] = (short)f2b(s[e]);
  *(short8*)&Cp[i] = h;
}

// ---------------------------------------------------------------- GEMM2
// out[4096][4096](f32) = (Cb @ GoT^T) * scale, scale = 1/(4096*sum(w))
// BM=BN=128, BK=32, dbuf LDS (16 KB/stage -> 32 KB), one barrier/stage.
__global__ __launch_bounds__(256, 4) void gemm2_kernel(
    const ushort* __restrict__ Cb, const ushort* __restrict__ GoT,
    const float* __restrict__ w, float* __restrict__ out) {
  __shared__ __align__(16) ushort lds[2 * 8192];  // 32 KB: per buf A[8K] B[8K]
  const int tid = threadIdx.x, wid = tid >> 6, lane = tid & 63;
  const int m0 = blockIdx.y * 128, n0 = blockIdx.x * 128;
  const int wr = (wid >> 1) * 64, wc = (wid & 1) * 64;

  // fold wsum in: per-wave butterfly over the 256 weights
  float4 wv = *(const float4*)&w[lane * 4];
  float s = wv.x + wv.y + wv.z + wv.w;
  #pragma unroll
  for (int off = 32; off > 0; off >>= 1) s += __shfl_xor(s, off);
  const float scale = 1.0f / ((float)IN_FEAT * s);

  const int brow = lane >> 2;
  const int bswz = (((lane & 3) ^ ((lane >> 3) & 3)) << 3);
  const int fswz = ((lane >> 4) << 4) ^ ((((lane & 15) >> 1) & 3) << 4);

  f32x4 acc[4][4] = {};

  #define STAGE2(buf, k0)                                                    \
    _Pragma("unroll")                                                        \
    for (int q = 0; q < 2; ++q) {                                            \
      int c = wid * 2 + q;                                                   \
      int row = c * 16 + brow;                                               \
      gload_lds16(&Cb[(size_t)(m0 + row) * NCOMP + (k0) + bswz],             \
                  &lds[(buf) * 8192 + c * 512]);                             \
      gload_lds16(&GoT[(size_t)(n0 + row) * NCOMP + (k0) + bswz],            \
                  &lds[(buf) * 8192 + 4096 + c * 512]);                      \
    }

  STAGE2(0, 0)
  __syncthreads();

  for (int t = 0; t < 8; ++t) {
    if (t < 7) STAGE2((t + 1) & 1, (t + 1) * 32)
    const char* base = (const char*)lds + (t & 1) * 16384;
    bf16x8 af[4], bf[4];
    #pragma unroll
    for (int i = 0; i < 4; ++i)
      af[i] = ld_frag(base + (wr + i * 16 + (lane & 15)) * 64 + fswz);
    #pragma unroll
    for (int j = 0; j < 4; ++j)
      bf[j] = ld_frag(base + 8192 + (wc + j * 16 + (lane & 15)) * 64 + fswz);
    #pragma unroll
    for (int i = 0; i < 4; ++i)
      #pragma unroll
      for (int j = 0; j < 4; ++j)
        acc[i][j] = __builtin_amdgcn_mfma_f32_16x16x32_bf16(af[i], bf[j], acc[i][j], 0, 0, 0);
    __syncthreads();
  }
  #undef STAGE2

  #pragma unroll
  for (int i = 0; i < 4; ++i)
    #pragma unroll
    for (int r = 0; r < 4; ++r) {
      int row = m0 + wr + i * 16 + (lane >> 4) * 4 + r;
      #pragma unroll
      for (int j = 0; j < 4; ++j)
        out[(size_t)row * OUT_FEAT + n0 + wc + j * 16 + (lane & 15)] =
            acc[i][j][r] * scale;
    }
}

// ---------------------------------------------------------------- launch
extern "C" void kernel_launch(void* const* d_in, const int* in_sizes, int n_in,
                              void* d_out, int out_size, void* d_ws, size_t ws_size,
                              hipStream_t stream) {
  const float* x   = (const float*)d_in[0];
  const float* mus = (const float*)d_in[1];
  const float* lvs = (const float*)d_in[2];
  const float* w   = (const float*)d_in[3];
  float* out = (float*)d_out;

  ushort* Gt  = (ushort*)d_ws;                      // [256][4096] bf16, 2 MiB
  ushort* GoT = Gt  + (size_t)NCOMP * IN_FEAT;      // [4096][256] bf16, 2 MiB
  ushort* Cpart = GoT + (size_t)OUT_FEAT * NCOMP;   // NS x 2 MiB (bf16); Cb = Cpart[0]

  const size_t MiB = 1024 * 1024;
  int nsplit = 16;
  while (nsplit > 1 && ws_size < 4 * MiB + (size_t)nsplit * 2 * MiB) nsplit >>= 1;

  prep_kernel<<<(NCOMP * IN_FEAT + OUT_FEAT * NCOMP) / 256, 256, 0, stream>>>(
      mus, lvs, w, Gt, GoT);

  dim3 g1(BATCH / 64, nsplit);
  switch (nsplit) {
    case 16: gemm1_kernel<16><<<g1, 256, 0, stream>>>(x, Gt, Cpart);
             reduce_kernel<16><<<BATCH * NCOMP / 8 / 256, 256, 0, stream>>>(Cpart);
             break;
    case 8:  gemm1_kernel<8><<<g1, 256, 0, stream>>>(x, Gt, Cpart);
             reduce_kernel<8><<<BATCH * NCOMP / 8 / 256, 256, 0, stream>>>(Cpart);
             break;
    case 4:  gemm1_kernel<4><<<g1, 256, 0, stream>>>(x, Gt, Cpart);
             reduce_kernel<4><<<BATCH * NCOMP / 8 / 256, 256, 0, stream>>>(Cpart);
             break;
    case 2:  gemm1_kernel<2><<<g1, 256, 0, stream>>>(x, Gt, Cpart);
             reduce_kernel<2><<<BATCH * NCOMP / 8 / 256, 256, 0, stream>>>(Cpart);
             break;
    default: gemm1_kernel<1><<<g1, 256, 0, stream>>>(x, Gt, Cpart);
             break;
  }

  gemm2_kernel<<<dim3(OUT_FEAT / 128, BATCH / 128), 256, 0, stream>>>(
      Cpart, GoT, w, out);
}